// Round 3
// baseline (1237.465 us; speedup 1.0000x reference)
//
#include <hip/hip_runtime.h>

typedef unsigned int u32;
typedef unsigned short u16;
typedef __bf16 bf16x8 __attribute__((ext_vector_type(8)));
typedef float f32x16 __attribute__((ext_vector_type(16)));
typedef float f32x4v __attribute__((ext_vector_type(4)));
typedef u32 u32x4 __attribute__((ext_vector_type(4)));
typedef u32 u32x2 __attribute__((ext_vector_type(2)));

#define BATCH    32768
#define DIN      256
#define UNITS    512
#define BM       64
#define NTHREADS 1024
#define NSTEP    6
#define DT       (1.0f/6.0f)
#define SMEM_BYTES (65536 + 65536)

__device__ __forceinline__ u16 f2bf(float f) {
  return __builtin_bit_cast(u16, (__bf16)f);
}
__device__ __forceinline__ float bf2f(u16 b) {
  return __builtin_bit_cast(float, (u32)b << 16);
}
__device__ __forceinline__ u32 pk2(float a, float b) {
  return (u32)f2bf(a) | ((u32)f2bf(b) << 16);
}
__device__ __forceinline__ float fast_tanh(float x) {
  float t = fminf(fmaxf(x * 2.885390082f, -60.f), 60.f);
  float a = __builtin_amdgcn_exp2f(t);
  return (a - 1.f) * __builtin_amdgcn_rcpf(a + 1.f);
}

// Pack K (256x512) and R (512x512) f32 row-major into bf16 B-fragment order:
// chunk c = g*512 + n holds rows g*8..g*8+7, col n (16B per lane).
__global__ void pack_weights(const float* __restrict__ Km, const float* __restrict__ Rm,
                             u16* __restrict__ Kp, u16* __restrict__ Rp) {
  int c = blockIdx.x * 256 + threadIdx.x;          // 0 .. 49151
  if (c < 32768) {
    int n = c & 511, g = c >> 9;                   // g < 64
    u32x4 p;
#pragma unroll
    for (int i = 0; i < 4; ++i) {
      u16 lo = f2bf(Rm[(g * 8 + 2 * i) * 512 + n]);
      u16 hh = f2bf(Rm[(g * 8 + 2 * i + 1) * 512 + n]);
      p[i] = (u32)lo | ((u32)hh << 16);
    }
    ((u32x4*)Rp)[c] = p;
  } else {
    int c2 = c - 32768;                            // < 16384
    int n = c2 & 511, g = c2 >> 9;                 // g < 32
    u32x4 p;
#pragma unroll
    for (int i = 0; i < 4; ++i) {
      u16 lo = f2bf(Km[(g * 8 + 2 * i) * 512 + n]);
      u16 hh = f2bf(Km[(g * 8 + 2 * i + 1) * 512 + n]);
      p[i] = (u32)lo | ((u32)hh << 16);
    }
    ((u32x4*)Kp)[c2] = p;
  }
}

__global__ __launch_bounds__(NTHREADS, 4)
void ctrnn_fused(const float* __restrict__ X, const float* __restrict__ H0,
                 const u16* __restrict__ Kp, const u16* __restrict__ Rp,
                 const float* __restrict__ bias, const float* __restrict__ scale,
                 float* __restrict__ out) {
  extern __shared__ char smem[];
  char* heL  = smem;            // 64KB: he [64 rows][512 cols] bf16, pitch 1024B, swizzled; x-stage in prologue
  char* xkbL = smem + 65536;    // 64KB: xkb bf16, fragment-linear [wv][rt][q][lane][16B]

  const int tid  = threadIdx.x;
  const int lane = tid & 63;
  const int wv   = tid >> 6;             // 0..15  (1 x 16 wave grid: wave = unique 32-col slice)
  const int ln   = lane & 31, hi = lane >> 5;
  const long r0  = (long)blockIdx.x * BM;

  const int jc  = wv * 32 + ln;          // this thread's output column
  const int swA = (ln & 7) << 4;

  // stage x tile -> bf16 LDS [64][256], rows 512B pitch, swizzle ^((m&7)<<4)
  {
    const f32x4v* X4 = (const f32x4v*)(X + r0 * DIN);
#pragma unroll
    for (int i = 0; i < 4; ++i) {
      int flat = i * NTHREADS + tid;     // 0..4095 float4-chunks
      int m = flat >> 6, c4 = flat & 63;
      f32x4v v = X4[m * 64 + c4];
      u32x2 p;
      p.x = pk2(v.x, v.y);
      p.y = pk2(v.z, v.w);
      *(u32x2*)(heL + m * 512 + ((c4 * 8) ^ ((m & 7) << 4))) = p;
    }
  }

  const float scl = scale[jc];

  __syncthreads();

  // ---- prologue: xkb = x @ K + bias (MFMA over DIN=256, 16 k-blocks) ----
  {
    f32x16 pre[2];
    {
      float b = bias[jc];
#pragma unroll
      for (int r = 0; r < 16; ++r) { pre[0][r] = b; pre[1][r] = b; }
    }
    const u32x4* Kp4 = (const u32x4*)Kp;
#pragma unroll 2
    for (int kb = 0; kb < 16; ++kb) {
      bf16x8 a0 = __builtin_bit_cast(bf16x8,
          *(const u32x4*)(heL + ln * 512        + (((kb * 32) | (hi * 16)) ^ swA)));
      bf16x8 a1 = __builtin_bit_cast(bf16x8,
          *(const u32x4*)(heL + (32 + ln) * 512 + (((kb * 32) | (hi * 16)) ^ swA)));
      bf16x8 b = __builtin_bit_cast(bf16x8, Kp4[(kb * 2 + hi) * 512 + jc]);
      pre[0] = __builtin_amdgcn_mfma_f32_32x32x16_bf16(a0, b, pre[0], 0, 0, 0);
      pre[1] = __builtin_amdgcn_mfma_f32_32x32x16_bf16(a1, b, pre[1], 0, 0, 0);
    }
    // park xkb in LDS, fragment-linear (lane*16 -> conflict-free)
#pragma unroll
    for (int rt = 0; rt < 2; ++rt) {
      u32x4 p0, p1;
#pragma unroll
      for (int i = 0; i < 4; ++i) {
        p0[i] = pk2(pre[rt][2 * i],     pre[rt][2 * i + 1]);
        p1[i] = pk2(pre[rt][8 + 2 * i], pre[rt][9 + 2 * i]);
      }
      int base = ((wv * 2 + rt) * 2) * 1024 + lane * 16;
      *(u32x4*)(xkbL + base)        = p0;
      *(u32x4*)(xkbL + base + 1024) = p1;
    }
  }

  // load h (f32) in C-fragment layout; init hevP = bf16-packed he_1 (= h)
  float h[2][16];
  u32 accP[2][8];
  u32 hevP[2][8];
#pragma unroll
  for (int rt = 0; rt < 2; ++rt)
#pragma unroll
    for (int r = 0; r < 16; ++r) {
      int m = rt * 32 + (r & 3) + ((r >> 2) << 3) + hi * 4;
      h[rt][r] = H0[(r0 + m) * UNITS + jc];
    }
#pragma unroll
  for (int rt = 0; rt < 2; ++rt)
#pragma unroll
    for (int rp = 0; rp < 8; ++rp)
      hevP[rt][rp] = pk2(h[rt][2 * rp], h[rt][2 * rp + 1]);

  __syncthreads();   // all x-stage reads done; heL becomes the he buffer

  // write he_1 = bf16(h)
#pragma unroll
  for (int rt = 0; rt < 2; ++rt)
#pragma unroll
    for (int rp = 0; rp < 8; ++rp)
#pragma unroll
      for (int half = 0; half < 2; ++half) {
        int r = rp * 2 + half;
        int m = rt * 32 + (r & 3) + ((r >> 2) << 3) + hi * 4;
        *(u16*)(heL + m * 1024 + ((jc * 2) ^ ((m & 7) << 4))) =
            (u16)(half ? (hevP[rt][rp] >> 16) : (hevP[rt][rp] & 0xffffu));
      }
  __syncthreads();

  const u32x4* Rp4 = (const u32x4*)Rp;

  for (int step = 0; step < NSTEP; ++step) {
#pragma unroll
    for (int ev = 0; ev < 4; ++ev) {
      // pre = xkb (re-init from LDS, own-thread data)
      f32x16 pre[2];
#pragma unroll
      for (int rt = 0; rt < 2; ++rt) {
        int base = ((wv * 2 + rt) * 2) * 1024 + lane * 16;
        u32x4 q0 = *(const u32x4*)(xkbL + base);
        u32x4 q1 = *(const u32x4*)(xkbL + base + 1024);
#pragma unroll
        for (int i = 0; i < 4; ++i) {
          pre[rt][2 * i]     = bf2f((u16)(q0[i] & 0xffffu));
          pre[rt][2 * i + 1] = bf2f((u16)(q0[i] >> 16));
          pre[rt][8 + 2 * i] = bf2f((u16)(q1[i] & 0xffffu));
          pre[rt][9 + 2 * i] = bf2f((u16)(q1[i] >> 16));
        }
      }
      // pre += he @ R  (32 k-blocks; one shared B-frag per kb, two row tiles)
#pragma unroll 2
      for (int kb = 0; kb < 32; ++kb) {
        bf16x8 a0 = __builtin_bit_cast(bf16x8,
            *(const u32x4*)(heL + ln * 1024        + (((kb * 32) | (hi * 16)) ^ swA)));
        bf16x8 a1 = __builtin_bit_cast(bf16x8,
            *(const u32x4*)(heL + (32 + ln) * 1024 + (((kb * 32) | (hi * 16)) ^ swA)));
        bf16x8 b = __builtin_bit_cast(bf16x8, Rp4[(kb * 2 + hi) * 512 + jc]);
        pre[0] = __builtin_amdgcn_mfma_f32_32x32x16_bf16(a0, b, pre[0], 0, 0, 0);
        pre[1] = __builtin_amdgcn_mfma_f32_32x32x16_bf16(a1, b, pre[1], 0, 0, 0);
      }

      // epilogue: k = scale*tanh(pre) - he ; RK4 bookkeeping (all in-register)
      const float wk = (ev == 1 || ev == 2) ? 2.f : 1.f;
      const float ce = (ev < 2) ? (DT * 0.5f) : DT;
#pragma unroll
      for (int rt = 0; rt < 2; ++rt) {
#pragma unroll
        for (int rp = 0; rp < 8; ++rp) {
          float hev0 = bf2f((u16)(hevP[rt][rp] & 0xffffu));
          float hev1 = bf2f((u16)(hevP[rt][rp] >> 16));
          float k0 = scl * fast_tanh(pre[rt][2 * rp])     - hev0;
          float k1 = scl * fast_tanh(pre[rt][2 * rp + 1]) - hev1;
          float a0 = (ev == 0 ? 0.f : bf2f((u16)(accP[rt][rp] & 0xffffu))) + wk * k0;
          float a1 = (ev == 0 ? 0.f : bf2f((u16)(accP[rt][rp] >> 16)))     + wk * k1;
          float n0, n1;
          if (ev == 3) {
            h[rt][2 * rp]     += (DT / 6.f) * a0;
            h[rt][2 * rp + 1] += (DT / 6.f) * a1;
            n0 = h[rt][2 * rp];
            n1 = h[rt][2 * rp + 1];
          } else {
            accP[rt][rp] = pk2(a0, a1);
            n0 = h[rt][2 * rp]     + ce * k0;
            n1 = h[rt][2 * rp + 1] + ce * k1;
          }
          hevP[rt][rp] = pk2(n0, n1);   // == bits written to LDS below
        }
      }
      __syncthreads();   // all MFMA reads of heL complete

      // write he_next
      if (!(step == NSTEP - 1 && ev == 3)) {
#pragma unroll
        for (int rt = 0; rt < 2; ++rt)
#pragma unroll
          for (int rp = 0; rp < 8; ++rp)
#pragma unroll
            for (int half = 0; half < 2; ++half) {
              int r = rp * 2 + half;
              int m = rt * 32 + (r & 3) + ((r >> 2) << 3) + hi * 4;
              *(u16*)(heL + m * 1024 + ((jc * 2) ^ ((m & 7) << 4))) =
                  (u16)(half ? (hevP[rt][rp] >> 16) : (hevP[rt][rp] & 0xffffu));
            }
      }
      __syncthreads();   // he_{i+1} visible
    }
  }

  // store final h
#pragma unroll
  for (int rt = 0; rt < 2; ++rt)
#pragma unroll
    for (int r = 0; r < 16; ++r) {
      int m = rt * 32 + (r & 3) + ((r >> 2) << 3) + hi * 4;
      out[(r0 + m) * UNITS + jc] = h[rt][r];
    }
}

extern "C" void kernel_launch(void* const* d_in, const int* in_sizes, int n_in,
                              void* d_out, int out_size, void* d_ws, size_t ws_size,
                              hipStream_t stream) {
  const float* X     = (const float*)d_in[0];
  const float* H0    = (const float*)d_in[1];
  const float* Km    = (const float*)d_in[2];
  const float* Rm    = (const float*)d_in[3];
  const float* bias  = (const float*)d_in[4];
  const float* scale = (const float*)d_in[5];
  float* out = (float*)d_out;

  u16* Rp = (u16*)d_ws;                  // 512*512 bf16 = 512KB
  u16* Kp = Rp + UNITS * UNITS;          // 256*512 bf16 = 256KB

  (void)hipFuncSetAttribute((const void*)ctrnn_fused,
                            hipFuncAttributeMaxDynamicSharedMemorySize, SMEM_BYTES);

  pack_weights<<<192, 256, 0, stream>>>(Km, Rm, Kp, Rp);
  ctrnn_fused<<<BATCH / BM, NTHREADS, SMEM_BYTES, stream>>>(X, H0, Kp, Rp, bias, scale, out);
}

// Round 4
// 816.074 us; speedup vs baseline: 1.5164x; 1.5164x over previous
//
#include <hip/hip_runtime.h>

typedef unsigned int u32;
typedef unsigned short u16;
typedef __bf16 bf16x8 __attribute__((ext_vector_type(8)));
typedef float f32x16 __attribute__((ext_vector_type(16)));
typedef float f32x4v __attribute__((ext_vector_type(4)));
typedef u32 u32x4 __attribute__((ext_vector_type(4)));
typedef u32 u32x2 __attribute__((ext_vector_type(2)));

#define BATCH    32768
#define DIN      256
#define UNITS    512
#define BM       32
#define NTHREADS 1024
#define NSTEP    6
#define DT       (1.0f/6.0f)

__device__ __forceinline__ u16 f2bf(float f) {
  return __builtin_bit_cast(u16, (__bf16)f);
}
__device__ __forceinline__ float bf2f(u16 b) {
  return __builtin_bit_cast(float, (u32)b << 16);
}
__device__ __forceinline__ u32 pk2(float a, float b) {
  return (u32)f2bf(a) | ((u32)f2bf(b) << 16);
}
__device__ __forceinline__ float fast_tanh(float x) {
  float t = fminf(fmaxf(x * 2.885390082f, -60.f), 60.f);
  float a = __builtin_amdgcn_exp2f(t);
  return (a - 1.f) * __builtin_amdgcn_rcpf(a + 1.f);
}

// Pack K (256x512) and R (512x512) f32 row-major into bf16 B-fragment order:
// chunk c = g*512 + n holds rows g*8..g*8+7, col n (16B per lane).
__global__ void pack_weights(const float* __restrict__ Km, const float* __restrict__ Rm,
                             u16* __restrict__ Kp, u16* __restrict__ Rp) {
  int c = blockIdx.x * 256 + threadIdx.x;          // 0 .. 49151
  if (c < 32768) {
    int n = c & 511, g = c >> 9;                   // g < 64
    u32x4 p;
#pragma unroll
    for (int i = 0; i < 4; ++i) {
      u16 lo = f2bf(Rm[(g * 8 + 2 * i) * 512 + n]);
      u16 hh = f2bf(Rm[(g * 8 + 2 * i + 1) * 512 + n]);
      p[i] = (u32)lo | ((u32)hh << 16);
    }
    ((u32x4*)Rp)[c] = p;
  } else {
    int c2 = c - 32768;                            // < 16384
    int n = c2 & 511, g = c2 >> 9;                 // g < 32
    u32x4 p;
#pragma unroll
    for (int i = 0; i < 4; ++i) {
      u16 lo = f2bf(Km[(g * 8 + 2 * i) * 512 + n]);
      u16 hh = f2bf(Km[(g * 8 + 2 * i + 1) * 512 + n]);
      p[i] = (u32)lo | ((u32)hh << 16);
    }
    ((u32x4*)Kp)[c2] = p;
  }
}

__global__ __launch_bounds__(NTHREADS, 4)
void ctrnn_fused(const float* __restrict__ X, const float* __restrict__ H0,
                 const u16* __restrict__ Kp, const u16* __restrict__ Rp,
                 const float* __restrict__ bias, const float* __restrict__ scale,
                 float* __restrict__ out) {
  // 32KB: he [32 rows][512 cols] bf16, pitch 1024B, swizzled ^((m&7)<<4).
  // Prologue stages x here first ([32][256] bf16, pitch 512B, same swizzle).
  __shared__ char heL[32768];

  const int tid  = threadIdx.x;
  const int lane = tid & 63;
  const int wv   = tid >> 6;             // 0..15 — wave owns cols [wv*32, wv*32+32)
  const int ln   = lane & 31, hi = lane >> 5;
  const long r0  = (long)blockIdx.x * BM;

  const int jc  = wv * 32 + ln;          // this thread's output column
  const int swA = (ln & 7) << 4;

  // stage x tile -> bf16 LDS [32][256], pitch 512B
  {
    const f32x4v* X4 = (const f32x4v*)(X + r0 * DIN);
#pragma unroll
    for (int i = 0; i < 2; ++i) {
      int flat = i * NTHREADS + tid;     // 0..2047 float4-chunks
      int m = flat >> 6, c4 = flat & 63;
      f32x4v v = X4[m * 64 + c4];
      u32x2 p;
      p.x = pk2(v.x, v.y);
      p.y = pk2(v.z, v.w);
      *(u32x2*)(heL + m * 512 + ((c4 * 8) ^ ((m & 7) << 4))) = p;
    }
  }

  const float scl = scale[jc];

  __syncthreads();

  // ---- prologue: xkb = x @ K + bias -> packed bf16 in regs (xkbP) ----
  u32 xkbP[8];
  {
    f32x16 pre;
    {
      float b = bias[jc];
#pragma unroll
      for (int r = 0; r < 16; ++r) pre[r] = b;
    }
    const u32x4* Kp4 = (const u32x4*)Kp;
#pragma unroll 2
    for (int kb = 0; kb < 16; ++kb) {
      bf16x8 a = __builtin_bit_cast(bf16x8,
          *(const u32x4*)(heL + ln * 512 + (((kb * 32) | (hi * 16)) ^ swA)));
      bf16x8 b = __builtin_bit_cast(bf16x8, Kp4[(kb * 2 + hi) * 512 + jc]);
      pre = __builtin_amdgcn_mfma_f32_32x32x16_bf16(a, b, pre, 0, 0, 0);
    }
#pragma unroll
    for (int i = 0; i < 8; ++i)
      xkbP[i] = pk2(pre[2 * i], pre[2 * i + 1]);
  }

  // load h (f32) in C-fragment layout; init hevP = bf16(he_1 = h)
  float h[16];
  u32 accP[8];
  u32 hevP[8];
#pragma unroll
  for (int r = 0; r < 16; ++r) {
    int m = (r & 3) + ((r >> 2) << 3) + hi * 4;
    h[r] = H0[(r0 + m) * UNITS + jc];
  }
#pragma unroll
  for (int rp = 0; rp < 8; ++rp)
    hevP[rp] = pk2(h[2 * rp], h[2 * rp + 1]);

  __syncthreads();   // all prologue reads of x-region done; heL becomes he buffer

  // write he_1 = bf16(h)
#pragma unroll
  for (int rp = 0; rp < 8; ++rp)
#pragma unroll
    for (int half = 0; half < 2; ++half) {
      int r = rp * 2 + half;
      int m = (r & 3) + ((r >> 2) << 3) + hi * 4;
      *(u16*)(heL + m * 1024 + ((jc * 2) ^ ((m & 7) << 4))) =
          (u16)(half ? (hevP[rp] >> 16) : (hevP[rp] & 0xffffu));
    }
  __syncthreads();

  const u32x4* Rp4 = (const u32x4*)Rp;

  for (int step = 0; step < NSTEP; ++step) {
#pragma unroll
    for (int ev = 0; ev < 4; ++ev) {
      // pre = xkb (register unpack)
      f32x16 pre;
#pragma unroll
      for (int i = 0; i < 8; ++i) {
        pre[2 * i]     = bf2f((u16)(xkbP[i] & 0xffffu));
        pre[2 * i + 1] = bf2f((u16)(xkbP[i] >> 16));
      }
      // pre += he @ R  (32 k-blocks; B frags streamed from L2)
#pragma unroll 2
      for (int kb = 0; kb < 32; ++kb) {
        bf16x8 a = __builtin_bit_cast(bf16x8,
            *(const u32x4*)(heL + ln * 1024 + (((kb * 32) | (hi * 16)) ^ swA)));
        bf16x8 b = __builtin_bit_cast(bf16x8, Rp4[(kb * 2 + hi) * 512 + jc]);
        pre = __builtin_amdgcn_mfma_f32_32x32x16_bf16(a, b, pre, 0, 0, 0);
      }

      // epilogue: k = scale*tanh(pre) - he ; RK4 bookkeeping, all in-register
      const float wk = (ev == 1 || ev == 2) ? 2.f : 1.f;
      const float ce = (ev < 2) ? (DT * 0.5f) : DT;
#pragma unroll
      for (int rp = 0; rp < 8; ++rp) {
        float hev0 = bf2f((u16)(hevP[rp] & 0xffffu));
        float hev1 = bf2f((u16)(hevP[rp] >> 16));
        float k0 = scl * fast_tanh(pre[2 * rp])     - hev0;
        float k1 = scl * fast_tanh(pre[2 * rp + 1]) - hev1;
        float a0 = (ev == 0 ? 0.f : bf2f((u16)(accP[rp] & 0xffffu))) + wk * k0;
        float a1 = (ev == 0 ? 0.f : bf2f((u16)(accP[rp] >> 16)))     + wk * k1;
        float n0, n1;
        if (ev == 3) {
          h[2 * rp]     += (DT / 6.f) * a0;
          h[2 * rp + 1] += (DT / 6.f) * a1;
          n0 = h[2 * rp];
          n1 = h[2 * rp + 1];
        } else {
          accP[rp] = pk2(a0, a1);
          n0 = h[2 * rp]     + ce * k0;
          n1 = h[2 * rp + 1] + ce * k1;
        }
        hevP[rp] = pk2(n0, n1);
      }
      __syncthreads();   // all waves done reading heL for this eval

      // write he_next
      if (!(step == NSTEP - 1 && ev == 3)) {
#pragma unroll
        for (int rp = 0; rp < 8; ++rp)
#pragma unroll
          for (int half = 0; half < 2; ++half) {
            int r = rp * 2 + half;
            int m = (r & 3) + ((r >> 2) << 3) + hi * 4;
            *(u16*)(heL + m * 1024 + ((jc * 2) ^ ((m & 7) << 4))) =
                (u16)(half ? (hevP[rp] >> 16) : (hevP[rp] & 0xffffu));
          }
      }
      __syncthreads();   // he_{i+1} visible
    }
  }

  // store final h
#pragma unroll
  for (int r = 0; r < 16; ++r) {
    int m = (r & 3) + ((r >> 2) << 3) + hi * 4;
    out[(r0 + m) * UNITS + jc] = h[r];
  }
}

extern "C" void kernel_launch(void* const* d_in, const int* in_sizes, int n_in,
                              void* d_out, int out_size, void* d_ws, size_t ws_size,
                              hipStream_t stream) {
  const float* X     = (const float*)d_in[0];
  const float* H0    = (const float*)d_in[1];
  const float* Km    = (const float*)d_in[2];
  const float* Rm    = (const float*)d_in[3];
  const float* bias  = (const float*)d_in[4];
  const float* scale = (const float*)d_in[5];
  float* out = (float*)d_out;

  u16* Rp = (u16*)d_ws;                  // 512*512 bf16 = 512KB
  u16* Kp = Rp + UNITS * UNITS;          // 256*512 bf16 = 256KB

  pack_weights<<<192, 256, 0, stream>>>(Km, Rm, Kp, Rp);
  ctrnn_fused<<<BATCH / BM, NTHREADS, 0, stream>>>(X, H0, Kp, Rp, bias, scale, out);
}